// Round 7
// baseline (112.267 us; speedup 1.0000x reference)
//
#include <hip/hip_runtime.h>

#define BB 2
#define NN 512
#define INF 10
#define TI 64    // i-extent of output tile
#define TJ 32    // j-extent of output tile
#define FCH 128  // f per staging phase (2 phases, full f=256 accumulated in-block)

static __device__ __forceinline__ float dot4(float4 w, float4 v, float acc) {
    acc = fmaf(w.x, v.x, acc);
    acc = fmaf(w.y, v.y, acc);
    acc = fmaf(w.z, v.z, acc);
    acc = fmaf(w.w, v.w, acc);
    return acc;
}

// Kernel 1: per-point MLP chain (10->128->128->64) + projections to ha[256], hb[256]+bp0.
// 256 blocks x 256 threads, 4 points per block. Outputs f-contiguous: haT[point][f].
__global__ __launch_bounds__(256) void k_points(
    const float* __restrict__ x,
    const float* __restrict__ Ws0, const float* __restrict__ bs0,
    const float* __restrict__ Ws1, const float* __restrict__ bs1,
    const float* __restrict__ Ws2, const float* __restrict__ bs2,
    const float* __restrict__ Wp0, const float* __restrict__ bp0,
    float* __restrict__ haT, float* __restrict__ hbT)
{
    __shared__ __align__(16) float xs[4][INF];
    __shared__ __align__(16) float u0s[4][128];
    __shared__ __align__(16) float u1s[4][128];
    __shared__ __align__(16) float u2s[4][64];

    const int t  = threadIdx.x;
    const int p0 = blockIdx.x * 4;

    if (t < 4 * INF) {
        int p = t / INF, c = t % INF;
        xs[p][c] = x[(p0 + p) * INF + c];
    }
    __syncthreads();

    {   // layer 0: 10 -> 128
        const int f = t & 127, ph = t >> 7;
        float a0 = bs0[f], a1 = a0;
        #pragma unroll
        for (int c = 0; c < INF; ++c) {
            float w = Ws0[f * INF + c];
            a0 = fmaf(w, xs[ph * 2 + 0][c], a0);
            a1 = fmaf(w, xs[ph * 2 + 1][c], a1);
        }
        u0s[ph * 2 + 0][f] = fmaxf(a0, 0.f);
        u0s[ph * 2 + 1][f] = fmaxf(a1, 0.f);
    }
    __syncthreads();

    {   // layer 1: 128 -> 128
        const int f = t & 127, ph = t >> 7;
        float a0 = bs1[f], a1 = a0;
        const float4* wv = (const float4*)(Ws1 + f * 128);
        #pragma unroll 8
        for (int c4 = 0; c4 < 32; ++c4) {
            float4 w  = wv[c4];
            float4 x0 = *(const float4*)&u0s[ph * 2 + 0][c4 * 4];
            float4 x1 = *(const float4*)&u0s[ph * 2 + 1][c4 * 4];
            a0 = dot4(w, x0, a0);
            a1 = dot4(w, x1, a1);
        }
        u1s[ph * 2 + 0][f] = fmaxf(a0, 0.f);
        u1s[ph * 2 + 1][f] = fmaxf(a1, 0.f);
    }
    __syncthreads();

    {   // layer 2: 128 -> 64
        const int f = t & 63, p = t >> 6;
        float a = bs2[f];
        const float4* wv = (const float4*)(Ws2 + f * 128);
        #pragma unroll 8
        for (int c4 = 0; c4 < 32; ++c4) {
            float4 w  = wv[c4];
            float4 xv = *(const float4*)&u1s[p][c4 * 4];
            a = dot4(w, xv, a);
        }
        u2s[p][f] = fmaxf(a, 0.f);
    }
    __syncthreads();

    {   // projection to ha / hb(+bp0)
        const int f = t;
        float ah[4], bh[4];
        const float bb = bp0[f];
        #pragma unroll
        for (int p = 0; p < 4; ++p) { ah[p] = 0.f; bh[p] = bb; }
        const float4* wv = (const float4*)(Wp0 + f * 128);
        #pragma unroll 4
        for (int c4 = 0; c4 < 16; ++c4) {
            float4 wa = wv[c4];
            float4 wb = wv[16 + c4];
            #pragma unroll
            for (int p = 0; p < 4; ++p) {
                float4 u = *(const float4*)&u2s[p][c4 * 4];
                ah[p] = dot4(wa, u, ah[p]);
                bh[p] = dot4(wb, u, bh[p]);
            }
        }
        #pragma unroll
        for (int p = 0; p < 4; ++p) {
            haT[(size_t)(p0 + p) * 256 + f] = ah[p];
            hbT[(size_t)(p0 + p) * 256 + f] = bh[p];
        }
    }
}

// Kernel 2: out[b,i,j] = bp1 + sum_{f=0..255} w[f]*relu(ha[b,f,j] + hb'(b,f,i)).
// Full f per block (2 staged phases of 128 f); d_out written once, densely. Grid (16,8,2)=256.
// 256 threads = 4 waves; wave w owns i in [w*16, w*16+16); lane: li=lane>>4 (i), lj=lane&15 (j).
// Register tile 4(i) x 2(j). LDS 16B-granule swizzle applied by pre-swizzling the GLOBAL
// source granule, dense LDS writes (m173 pattern). Reads: 32-bit element-index XOR so clang
// keeps addrspace(3) and emits ds_read_b128 (NOT uintptr_t flat loads — round-6 regression).
// sA reads 2-way bank conflicts (free), sB reads conflict-free.
// Phase-1 staging data prefetched into registers during phase-0 compute (T14 split).
__global__ __launch_bounds__(256) void k_outer(
    const float* __restrict__ haT, const float* __restrict__ hbT,
    const float* __restrict__ Wp1, const float* __restrict__ bp1,
    float* __restrict__ out)
{
    __shared__ __align__(512) float sA[TJ * FCH];   // 32 j-rows x 128 f = 16 KB
    __shared__ __align__(512) float sB[TI * FCH];   // 64 i-rows x 128 f = 32 KB

    const int t  = threadIdx.x;
    const int jb = blockIdx.x * TJ;
    const int ib = blockIdx.y * TI;
    const int b  = blockIdx.z;

    const int lane = t & 63, w = t >> 6;
    const int lj = lane & 15;           // j-group 0..15
    const int li = lane >> 4;           // i-group 0..3
    const int j0 = lj * 2;              // 2 consecutive j rows
    const int i0 = w * 16 + li * 4;     // 4 consecutive i rows
    const int xa = lj;                  // (row>>1)&15 for rows j0, j0+1
    const int xb = w * 4 + li;          // (row>>2)&15 for rows i0..i0+3

    // element-index bases (stay in LDS address space)
    const int aOff0 = j0 * FCH;
    const int aOff1 = aOff0 + FCH;
    const int bOff0 = i0 * FCH;

    float acc[4][2];
    #pragma unroll
    for (int di = 0; di < 4; ++di) { acc[di][0] = 0.f; acc[di][1] = 0.f; }

    const int sp = t & 31;              // staging granule slot (constant per thread)
    const int sr = t >> 5;              // staging row base

    // ---- phase 0 staging: dense LDS writes, pre-swizzled global source granule ----
    #pragma unroll
    for (int k = 0; k < 4; ++k) {
        const int r  = sr + 8 * k;                       // row 0..31
        const int sg = sp ^ ((r >> 1) & 15);
        float4 v = *(const float4*)(haT + ((size_t)(b * NN + jb + r)) * 256 + sg * 4);
        *(float4*)&sA[r * FCH + sp * 4] = v;
    }
    #pragma unroll
    for (int k = 0; k < 8; ++k) {
        const int r  = sr + 8 * k;                       // row 0..63
        const int sg = sp ^ ((r >> 2) & 15);
        float4 v = *(const float4*)(hbT + ((size_t)(b * NN + ib + r)) * 256 + sg * 4);
        *(float4*)&sB[r * FCH + sp * 4] = v;
    }
    __syncthreads();

    // ---- prefetch phase-1 staging into registers (in flight during phase-0 compute) ----
    float4 pfA[4], pfB[8];
    #pragma unroll
    for (int k = 0; k < 4; ++k) {
        const int r  = sr + 8 * k;
        const int sg = sp ^ ((r >> 1) & 15);
        pfA[k] = *(const float4*)(haT + ((size_t)(b * NN + jb + r)) * 256 + FCH + sg * 4);
    }
    #pragma unroll
    for (int k = 0; k < 8; ++k) {
        const int r  = sr + 8 * k;
        const int sg = sp ^ ((r >> 2) & 15);
        pfB[k] = *(const float4*)(hbT + ((size_t)(b * NN + ib + r)) * 256 + FCH + sg * 4);
    }

    auto compute = [&](const float4* wg) {
        #pragma unroll 8
        for (int g = 0; g < 32; ++g) {
            const float4 w4 = wg[g];
            const int ga = (g ^ xa) << 2;                // float offset within row
            const int gb = (g ^ xb) << 2;
            const float4 a0 = *(const float4*)&sA[aOff0 + ga];
            const float4 a1 = *(const float4*)&sA[aOff1 + ga];
            float4 bv[4];
            #pragma unroll
            for (int di = 0; di < 4; ++di)
                bv[di] = *(const float4*)&sB[bOff0 + di * FCH + gb];

            #pragma unroll
            for (int di = 0; di < 4; ++di) {
                acc[di][0] = fmaf(w4.x, fmaxf(a0.x + bv[di].x, 0.f), acc[di][0]);
                acc[di][1] = fmaf(w4.x, fmaxf(a1.x + bv[di].x, 0.f), acc[di][1]);
                acc[di][0] = fmaf(w4.y, fmaxf(a0.y + bv[di].y, 0.f), acc[di][0]);
                acc[di][1] = fmaf(w4.y, fmaxf(a1.y + bv[di].y, 0.f), acc[di][1]);
                acc[di][0] = fmaf(w4.z, fmaxf(a0.z + bv[di].z, 0.f), acc[di][0]);
                acc[di][1] = fmaf(w4.z, fmaxf(a1.z + bv[di].z, 0.f), acc[di][1]);
                acc[di][0] = fmaf(w4.w, fmaxf(a0.w + bv[di].w, 0.f), acc[di][0]);
                acc[di][1] = fmaf(w4.w, fmaxf(a1.w + bv[di].w, 0.f), acc[di][1]);
            }
        }
    };

    compute((const float4*)Wp1);          // phase 0 (f 0..127)
    __syncthreads();

    // ---- phase 1 staging from registers ----
    #pragma unroll
    for (int k = 0; k < 4; ++k) {
        const int r = sr + 8 * k;
        *(float4*)&sA[r * FCH + sp * 4] = pfA[k];
    }
    #pragma unroll
    for (int k = 0; k < 8; ++k) {
        const int r = sr + 8 * k;
        *(float4*)&sB[r * FCH + sp * 4] = pfB[k];
    }
    __syncthreads();

    compute((const float4*)(Wp1 + FCH));  // phase 1 (f 128..255)

    // store: per thread 4 rows x float2; wave covers 128B dense per i-row
    const float bias = bp1[0];
    float* o = out + (size_t)b * NN * NN;
    #pragma unroll
    for (int di = 0; di < 4; ++di) {
        float2 v = { acc[di][0] + bias, acc[di][1] + bias };
        *(float2*)&o[(size_t)(ib + i0 + di) * NN + (jb + j0)] = v;
    }
}

extern "C" void kernel_launch(void* const* d_in, const int* in_sizes, int n_in,
                              void* d_out, int out_size, void* d_ws, size_t ws_size,
                              hipStream_t stream) {
    const float* x   = (const float*)d_in[0];
    const float* Ws0 = (const float*)d_in[1];
    const float* bs0 = (const float*)d_in[2];
    const float* Ws1 = (const float*)d_in[3];
    const float* bs1 = (const float*)d_in[4];
    const float* Ws2 = (const float*)d_in[5];
    const float* bs2 = (const float*)d_in[6];
    const float* Wp0 = (const float*)d_in[7];
    const float* bp0 = (const float*)d_in[8];
    const float* Wp1 = (const float*)d_in[9];
    const float* bp1 = (const float*)d_in[10];

    float* haT = (float*)d_ws;                      // [1024][256] = 1 MB
    float* hbT = haT + (size_t)BB * NN * 256;       // [1024][256] = 1 MB

    k_points<<<dim3(BB * NN / 4), dim3(256), 0, stream>>>(
        x, Ws0, bs0, Ws1, bs1, Ws2, bs2, Wp0, bp0, haT, hbT);

    k_outer<<<dim3(NN / TJ, NN / TI, BB), dim3(256), 0, stream>>>(
        haT, hbT, Wp1, bp1, (float*)d_out);
}

// Round 12
// 108.820 us; speedup vs baseline: 1.0317x; 1.0317x over previous
//
#include <hip/hip_runtime.h>

#define BB 2
#define NN 512
#define INF 10
#define TI 64    // i-extent of output tile
#define TJ 32    // j-extent of output tile
#define FCH 128  // f per staging phase (2 phases, full f=256 accumulated in-block)

static __device__ __forceinline__ float dot4(float4 w, float4 v, float acc) {
    acc = fmaf(w.x, v.x, acc);
    acc = fmaf(w.y, v.y, acc);
    acc = fmaf(w.z, v.z, acc);
    acc = fmaf(w.w, v.w, acc);
    return acc;
}

// Kernel 1: per-point MLP chain (10->128->128->64) + projections to ha[256], hb[256]+bp0.
// 256 blocks x 256 threads, 4 points per block. Outputs f-contiguous: haT[point][f].
__global__ __launch_bounds__(256) void k_points(
    const float* __restrict__ x,
    const float* __restrict__ Ws0, const float* __restrict__ bs0,
    const float* __restrict__ Ws1, const float* __restrict__ bs1,
    const float* __restrict__ Ws2, const float* __restrict__ bs2,
    const float* __restrict__ Wp0, const float* __restrict__ bp0,
    float* __restrict__ haT, float* __restrict__ hbT)
{
    __shared__ __align__(16) float xs[4][INF];
    __shared__ __align__(16) float u0s[4][128];
    __shared__ __align__(16) float u1s[4][128];
    __shared__ __align__(16) float u2s[4][64];

    const int t  = threadIdx.x;
    const int p0 = blockIdx.x * 4;

    if (t < 4 * INF) {
        int p = t / INF, c = t % INF;
        xs[p][c] = x[(p0 + p) * INF + c];
    }
    __syncthreads();

    {   // layer 0: 10 -> 128
        const int f = t & 127, ph = t >> 7;
        float a0 = bs0[f], a1 = a0;
        #pragma unroll
        for (int c = 0; c < INF; ++c) {
            float w = Ws0[f * INF + c];
            a0 = fmaf(w, xs[ph * 2 + 0][c], a0);
            a1 = fmaf(w, xs[ph * 2 + 1][c], a1);
        }
        u0s[ph * 2 + 0][f] = fmaxf(a0, 0.f);
        u0s[ph * 2 + 1][f] = fmaxf(a1, 0.f);
    }
    __syncthreads();

    {   // layer 1: 128 -> 128
        const int f = t & 127, ph = t >> 7;
        float a0 = bs1[f], a1 = a0;
        const float4* wv = (const float4*)(Ws1 + f * 128);
        #pragma unroll 8
        for (int c4 = 0; c4 < 32; ++c4) {
            float4 w  = wv[c4];
            float4 x0 = *(const float4*)&u0s[ph * 2 + 0][c4 * 4];
            float4 x1 = *(const float4*)&u0s[ph * 2 + 1][c4 * 4];
            a0 = dot4(w, x0, a0);
            a1 = dot4(w, x1, a1);
        }
        u1s[ph * 2 + 0][f] = fmaxf(a0, 0.f);
        u1s[ph * 2 + 1][f] = fmaxf(a1, 0.f);
    }
    __syncthreads();

    {   // layer 2: 128 -> 64
        const int f = t & 63, p = t >> 6;
        float a = bs2[f];
        const float4* wv = (const float4*)(Ws2 + f * 128);
        #pragma unroll 8
        for (int c4 = 0; c4 < 32; ++c4) {
            float4 w  = wv[c4];
            float4 xv = *(const float4*)&u1s[p][c4 * 4];
            a = dot4(w, xv, a);
        }
        u2s[p][f] = fmaxf(a, 0.f);
    }
    __syncthreads();

    {   // projection to ha / hb(+bp0)
        const int f = t;
        float ah[4], bh[4];
        const float bb = bp0[f];
        #pragma unroll
        for (int p = 0; p < 4; ++p) { ah[p] = 0.f; bh[p] = bb; }
        const float4* wv = (const float4*)(Wp0 + f * 128);
        #pragma unroll 4
        for (int c4 = 0; c4 < 16; ++c4) {
            float4 wa = wv[c4];
            float4 wb = wv[16 + c4];
            #pragma unroll
            for (int p = 0; p < 4; ++p) {
                float4 u = *(const float4*)&u2s[p][c4 * 4];
                ah[p] = dot4(wa, u, ah[p]);
                bh[p] = dot4(wb, u, bh[p]);
            }
        }
        #pragma unroll
        for (int p = 0; p < 4; ++p) {
            haT[(size_t)(p0 + p) * 256 + f] = ah[p];
            hbT[(size_t)(p0 + p) * 256 + f] = bh[p];
        }
    }
}

// Kernel 2: out[b,i,j] = bp1 + sum_{f=0..255} w[f]*relu(ha[b,f,j] + hb'(b,f,i)).
// Full f per block (2 staged phases of 128 f); d_out written once, densely.
// XCD-aware remap: linear block s -> logical lo=(s&7)*32+(s>>3), so each XCD
// (round-robin by s) owns 2 i-tiles x 16 j-tiles: per-XCD working set 640 KB, L2-resident.
// 256 threads = 4 waves; wave w owns i in [w*16,+16); li=lane>>4 (i), lj=lane&15 (j).
// Register tile 4(i) x 2(j). LDS 16B-granule XOR swizzle via pre-swizzled global source
// (m173); reads via 32-bit element indices (addrspace(3) preserved -> ds_read_b128).
// sA reads 2-way conflicts (free), sB conflict-free. Inner loop explicitly 2-stage
// software-pipelined: next f-group's 6 ds_reads issued before current group's FMAs
// (1 wave/SIMD occupancy -> latency must be hidden in-wave).
__global__ __launch_bounds__(256) void k_outer(
    const float* __restrict__ haT, const float* __restrict__ hbT,
    const float* __restrict__ Wp1, const float* __restrict__ bp1,
    float* __restrict__ out)
{
    __shared__ __align__(512) float sA[TJ * FCH];   // 32 j-rows x 128 f = 16 KB
    __shared__ __align__(512) float sB[TI * FCH];   // 64 i-rows x 128 f = 32 KB

    const int t = threadIdx.x;

    // XCD-aware bijective remap (grid 16x8x2 = 256 = 8 XCDs x 32 blocks)
    const int s  = blockIdx.x + blockIdx.y * 16 + blockIdx.z * 128;
    const int lo = (s & 7) * 32 + (s >> 3);
    const int jb = (lo & 15) * TJ;
    const int ib = ((lo >> 4) & 7) * TI;
    const int b  = lo >> 7;

    const int lane = t & 63, w = t >> 6;
    const int lj = lane & 15;           // j-group 0..15
    const int li = lane >> 4;           // i-group 0..3
    const int j0 = lj * 2;              // 2 consecutive j rows
    const int i0 = w * 16 + li * 4;     // 4 consecutive i rows
    const int xa = lj;                  // (row>>1)&15 for rows j0, j0+1
    const int xb = w * 4 + li;          // (row>>2)&15 for rows i0..i0+3

    const int aOff0 = j0 * FCH;
    const int aOff1 = aOff0 + FCH;
    const int bOff0 = i0 * FCH;

    float acc[4][2];
    #pragma unroll
    for (int di = 0; di < 4; ++di) { acc[di][0] = 0.f; acc[di][1] = 0.f; }

    const int sp = t & 31;              // staging granule slot (constant per thread)
    const int sr = t >> 5;              // staging row base

    // ---- phase 0 staging: dense LDS writes, pre-swizzled global source granule ----
    #pragma unroll
    for (int k = 0; k < 4; ++k) {
        const int r  = sr + 8 * k;                       // row 0..31
        const int sg = sp ^ ((r >> 1) & 15);
        float4 v = *(const float4*)(haT + ((size_t)(b * NN + jb + r)) * 256 + sg * 4);
        *(float4*)&sA[r * FCH + sp * 4] = v;
    }
    #pragma unroll
    for (int k = 0; k < 8; ++k) {
        const int r  = sr + 8 * k;                       // row 0..63
        const int sg = sp ^ ((r >> 2) & 15);
        float4 v = *(const float4*)(hbT + ((size_t)(b * NN + ib + r)) * 256 + sg * 4);
        *(float4*)&sB[r * FCH + sp * 4] = v;
    }
    __syncthreads();

    // ---- prefetch phase-1 staging into registers (in flight during phase-0 compute) ----
    float4 pfA[4], pfB[8];
    #pragma unroll
    for (int k = 0; k < 4; ++k) {
        const int r  = sr + 8 * k;
        const int sg = sp ^ ((r >> 1) & 15);
        pfA[k] = *(const float4*)(haT + ((size_t)(b * NN + jb + r)) * 256 + FCH + sg * 4);
    }
    #pragma unroll
    for (int k = 0; k < 8; ++k) {
        const int r  = sr + 8 * k;
        const int sg = sp ^ ((r >> 2) & 15);
        pfB[k] = *(const float4*)(hbT + ((size_t)(b * NN + ib + r)) * 256 + FCH + sg * 4);
    }

    // ---- 2-stage software-pipelined compute over one 128-f phase ----
    auto compute = [&](const float4* wg) {
        int ga = (0 ^ xa) << 2;
        int gb = (0 ^ xb) << 2;
        float4 a0 = *(const float4*)&sA[aOff0 + ga];
        float4 a1 = *(const float4*)&sA[aOff1 + ga];
        float4 b0 = *(const float4*)&sB[bOff0 + 0 * FCH + gb];
        float4 b1 = *(const float4*)&sB[bOff0 + 1 * FCH + gb];
        float4 b2 = *(const float4*)&sB[bOff0 + 2 * FCH + gb];
        float4 b3 = *(const float4*)&sB[bOff0 + 3 * FCH + gb];

        #pragma unroll
        for (int g = 0; g < 32; ++g) {
            float4 na0, na1, nb0, nb1, nb2, nb3;
            if (g < 31) {
                const int nga = ((g + 1) ^ xa) << 2;
                const int ngb = ((g + 1) ^ xb) << 2;
                na0 = *(const float4*)&sA[aOff0 + nga];
                na1 = *(const float4*)&sA[aOff1 + nga];
                nb0 = *(const float4*)&sB[bOff0 + 0 * FCH + ngb];
                nb1 = *(const float4*)&sB[bOff0 + 1 * FCH + ngb];
                nb2 = *(const float4*)&sB[bOff0 + 2 * FCH + ngb];
                nb3 = *(const float4*)&sB[bOff0 + 3 * FCH + ngb];
            }
            const float4 w4 = wg[g];

#define ROW(di, bv)                                                        \
            {                                                              \
                acc[di][0] = fmaf(w4.x, fmaxf(a0.x + bv.x, 0.f), acc[di][0]); \
                acc[di][1] = fmaf(w4.x, fmaxf(a1.x + bv.x, 0.f), acc[di][1]); \
                acc[di][0] = fmaf(w4.y, fmaxf(a0.y + bv.y, 0.f), acc[di][0]); \
                acc[di][1] = fmaf(w4.y, fmaxf(a1.y + bv.y, 0.f), acc[di][1]); \
                acc[di][0] = fmaf(w4.z, fmaxf(a0.z + bv.z, 0.f), acc[di][0]); \
                acc[di][1] = fmaf(w4.z, fmaxf(a1.z + bv.z, 0.f), acc[di][1]); \
                acc[di][0] = fmaf(w4.w, fmaxf(a0.w + bv.w, 0.f), acc[di][0]); \
                acc[di][1] = fmaf(w4.w, fmaxf(a1.w + bv.w, 0.f), acc[di][1]); \
            }
            ROW(0, b0) ROW(1, b1) ROW(2, b2) ROW(3, b3)
#undef ROW

            if (g < 31) {
                a0 = na0; a1 = na1;
                b0 = nb0; b1 = nb1; b2 = nb2; b3 = nb3;
            }
        }
    };

    compute((const float4*)Wp1);          // phase 0 (f 0..127)
    __syncthreads();

    // ---- phase 1 staging from registers ----
    #pragma unroll
    for (int k = 0; k < 4; ++k) {
        const int r = sr + 8 * k;
        *(float4*)&sA[r * FCH + sp * 4] = pfA[k];
    }
    #pragma unroll
    for (int k = 0; k < 8; ++k) {
        const int r = sr + 8 * k;
        *(float4*)&sB[r * FCH + sp * 4] = pfB[k];
    }
    __syncthreads();

    compute((const float4*)(Wp1 + FCH));  // phase 1 (f 128..255)

    // store: per thread 4 rows x float2; wave covers 128B dense per i-row
    const float bias = bp1[0];
    float* o = out + (size_t)b * NN * NN;
    #pragma unroll
    for (int di = 0; di < 4; ++di) {
        float2 v = { acc[di][0] + bias, acc[di][1] + bias };
        *(float2*)&o[(size_t)(ib + i0 + di) * NN + (jb + j0)] = v;
    }
}

extern "C" void kernel_launch(void* const* d_in, const int* in_sizes, int n_in,
                              void* d_out, int out_size, void* d_ws, size_t ws_size,
                              hipStream_t stream) {
    const float* x   = (const float*)d_in[0];
    const float* Ws0 = (const float*)d_in[1];
    const float* bs0 = (const float*)d_in[2];
    const float* Ws1 = (const float*)d_in[3];
    const float* bs1 = (const float*)d_in[4];
    const float* Ws2 = (const float*)d_in[5];
    const float* bs2 = (const float*)d_in[6];
    const float* Wp0 = (const float*)d_in[7];
    const float* bp0 = (const float*)d_in[8];
    const float* Wp1 = (const float*)d_in[9];
    const float* bp1 = (const float*)d_in[10];

    float* haT = (float*)d_ws;                      // [1024][256] = 1 MB
    float* hbT = haT + (size_t)BB * NN * 256;       // [1024][256] = 1 MB

    k_points<<<dim3(BB * NN / 4), dim3(256), 0, stream>>>(
        x, Ws0, bs0, Ws1, bs1, Ws2, bs2, Wp0, bp0, haT, hbT);

    k_outer<<<dim3(NN / TJ, NN / TI, BB), dim3(256), 0, stream>>>(
        haT, hbT, Wp1, bp1, (float*)d_out);
}